// Round 1
// baseline (141.848 us; speedup 1.0000x reference)
//
#include <hip/hip_runtime.h>

typedef float f32x4 __attribute__((ext_vector_type(4)));
typedef short short8 __attribute__((ext_vector_type(8)));
typedef unsigned short ushort8 __attribute__((ext_vector_type(8)));

// ---------------- workspace layout (ushort elements) ----------------
// WT (3 x [128][2048] bf16):      0 .. 786432
// Q  ([8*2048][128] bf16):        786432
// K  ([8*2048][128] bf16):        2883584
// Vt ([8][128][2048] bf16):       4980736   (total 7,077,888 u16 = 13.5 MiB)
#define WS_Q  786432
#define WS_K  2883584
#define WS_VT 4980736

__device__ __forceinline__ unsigned short f2bf(float x) {
    unsigned u = __float_as_uint(x);
    u += 0x7FFFu + ((u >> 16) & 1u);      // RNE
    return (unsigned short)(u >> 16);
}

// XOR swizzle for tiles with 128-byte rows (64 bf16): kills the 16/32-way
// bank conflict on ds_read_b128 of 16 different rows (guide §6 G4).
__device__ __forceinline__ int swz128(int row, int cbyte) {
    return row * 128 + (cbyte ^ ((row & 7) << 4));
}

// ================= K0: W [2048][128] fp32 -> WT [128][2048] bf16 ==========
__global__ __launch_bounds__(256) void wt_kernel(const float* __restrict__ Wq,
        const float* __restrict__ Wk, const float* __restrict__ Wv,
        unsigned short* __restrict__ ws) {
    __shared__ __align__(16) unsigned short tile[64][136];
    int mat = blockIdx.x >> 5, ct = blockIdx.x & 31;
    const float* W = (mat == 0) ? Wq : ((mat == 1) ? Wk : Wv);
    unsigned short* WT = ws + mat * 262144;
    int cbase = ct * 64;
    int tid = threadIdx.x;
#pragma unroll
    for (int p = 0; p < 8; p++) {
        int fidx = p * 256 + tid;          // float4 index, 2048 total
        int row = fidx >> 5;               // c within tile (0..63)
        int c4 = (fidx & 31) << 2;         // h (0..124)
        float4 v = *(const float4*)&W[(cbase + row) * 128 + c4];
        tile[row][c4 + 0] = f2bf(v.x);
        tile[row][c4 + 1] = f2bf(v.y);
        tile[row][c4 + 2] = f2bf(v.z);
        tile[row][c4 + 3] = f2bf(v.w);
    }
    __syncthreads();
    int h = tid >> 1, seg = tid & 1;
#pragma unroll
    for (int q4 = 0; q4 < 4; q4++) {
        ushort8 pk;
#pragma unroll
        for (int e = 0; e < 8; e++) pk[e] = tile[seg * 32 + q4 * 8 + e][h];
        *(ushort8*)&WT[h * 2048 + cbase + seg * 32 + q4 * 8] = pk;
    }
}

// ================= K1: QKV projection (bf16 MFMA) =========================
__device__ __forceinline__ void stage_tiles(const float* __restrict__ gx,
        const unsigned short* __restrict__ gw, unsigned short* smem, int tid) {
    // x tile [64 t][64 c] fp32 -> bf16, swizzled (8 KB at offset 0)
#pragma unroll
    for (int p = 0; p < 2; p++) {
        int e = p * 256 + tid;
        int row = e >> 3, c0 = (e & 7) << 3;
        const float* src = gx + row * 2048 + c0;
        float4 u0 = *(const float4*)src;
        float4 u1 = *(const float4*)(src + 4);
        ushort8 h;
        h[0] = f2bf(u0.x); h[1] = f2bf(u0.y); h[2] = f2bf(u0.z); h[3] = f2bf(u0.w);
        h[4] = f2bf(u1.x); h[5] = f2bf(u1.y); h[6] = f2bf(u1.z); h[7] = f2bf(u1.w);
        *(ushort8*)((char*)smem + swz128(row, c0 * 2)) = h;
    }
    // WT tile [128 h][64 c] bf16, swizzled (16 KB at byte offset 8192)
#pragma unroll
    for (int p = 0; p < 4; p++) {
        int e = p * 256 + tid;
        int hr = e >> 3, c0 = (e & 7) << 3;
        ushort8 v = *(const ushort8*)(gw + hr * 2048 + c0);
        *(ushort8*)((char*)smem + 8192 + swz128(hr, c0 * 2)) = v;
    }
}

template<int MF, int NF>
__device__ __forceinline__ void gemm_step(const unsigned short* smem, int aOff, int bOff,
        int m0, int n0, int lane, f32x4 (&acc)[MF][NF]) {
    int lr = lane & 15, lg = lane >> 4;
#pragma unroll
    for (int kf = 0; kf < 2; kf++) {
        int cb = kf * 64 + (lg << 4);
        short8 av[MF], bv8[NF];
#pragma unroll
        for (int i = 0; i < MF; i++)
            av[i] = *(const short8*)((const char*)smem + aOff + swz128(m0 + i * 16 + lr, cb));
#pragma unroll
        for (int jn = 0; jn < NF; jn++)
            bv8[jn] = *(const short8*)((const char*)smem + bOff + swz128(n0 + jn * 16 + lr, cb));
#pragma unroll
        for (int i = 0; i < MF; i++)
#pragma unroll
            for (int jn = 0; jn < NF; jn++)
                acc[i][jn] = __builtin_amdgcn_mfma_f32_16x16x32_bf16(av[i], bv8[jn], acc[i][jn], 0, 0, 0);
    }
}

__global__ __launch_bounds__(256) void qkv_kernel(const float* __restrict__ x,
        const float* __restrict__ bq, const float* __restrict__ bk,
        const float* __restrict__ bv, unsigned short* __restrict__ ws) {
    __shared__ __align__(16) unsigned short smem[12288];   // 24 KB
    // bid -> (mt, which) such that the 3 blocks of one m-tile are 8 apart
    // (same XCD under round-robin dispatch) -> x tile read once from HBM.
    int bid = blockIdx.x;
    int g = bid / 24, j = bid - g * 24;
    int which = j >> 3;                 // 0=Q 1=K 2=V
    int mt = g * 8 + (j & 7);           // 0..255 (64-row m tiles)
    const unsigned short* WT = ws + which * 262144;
    const float* x0 = x + (size_t)mt * 64 * 2048;
    int tid = threadIdx.x, lane = tid & 63, wid = tid >> 6;
    int lr = lane & 15, lg = lane >> 4;

    if (which < 2) {
        // C[t][h] = x . W  (A = x tile, B = WT tile)
        const float* bias = (which == 0) ? bq : bk;
        float sc = (which == 0) ? 0.08838834764831845f : 1.0f;  // H^-0.5 folded into Q
        f32x4 acc[2][4];
#pragma unroll
        for (int i = 0; i < 2; i++)
#pragma unroll
            for (int jn = 0; jn < 4; jn++) acc[i][jn] = (f32x4){0.f, 0.f, 0.f, 0.f};
        int m0 = (wid >> 1) * 32, n0 = (wid & 1) * 64;
        for (int ks = 0; ks < 32; ks++) {
            __syncthreads();
            stage_tiles(x0 + ks * 64, WT + ks * 64, smem, tid);
            __syncthreads();
            gemm_step<2, 4>(smem, 0, 8192, m0, n0, lane, acc);
        }
        unsigned short* outp = ws + ((which == 0) ? WS_Q : WS_K);
#pragma unroll
        for (int i = 0; i < 2; i++)
#pragma unroll
            for (int jn = 0; jn < 4; jn++) {
                int h = n0 + jn * 16 + lr;
                float bb = bias[h];
#pragma unroll
                for (int r = 0; r < 4; r++) {
                    int t = mt * 64 + m0 + i * 16 + (lg << 2) + r;
                    outp[(size_t)t * 128 + h] = f2bf((acc[i][jn][r] + bb) * sc);
                }
            }
    } else {
        // C[h][t] = WT . x^T  (A = WT tile, B = x tile) -> Vt directly
        f32x4 acc[4][2];
#pragma unroll
        for (int i = 0; i < 4; i++)
#pragma unroll
            for (int jn = 0; jn < 2; jn++) acc[i][jn] = (f32x4){0.f, 0.f, 0.f, 0.f};
        int m0 = (wid >> 1) * 64, n0 = (wid & 1) * 32;
        for (int ks = 0; ks < 32; ks++) {
            __syncthreads();
            stage_tiles(x0 + ks * 64, WT + ks * 64, smem, tid);
            __syncthreads();
            gemm_step<4, 2>(smem, 8192, 0, m0, n0, lane, acc);
        }
        // transpose through LDS for coalesced Vt stores
        __syncthreads();
#pragma unroll
        for (int i = 0; i < 4; i++)
#pragma unroll
            for (int r = 0; r < 4; r++) {
                int h = m0 + i * 16 + (lg << 2) + r;
                float bb = bv[h];
#pragma unroll
                for (int jn = 0; jn < 2; jn++) {
                    int t = n0 + jn * 16 + lr;
                    smem[t * 136 + h] = f2bf(acc[i][jn][r] + bb);
                }
            }
        __syncthreads();
        int h = tid & 127, seg = tid >> 7;
        int bb2 = mt >> 5;                    // batch
        int tin = (mt & 31) * 64 + seg * 32;  // t within batch
        unsigned short* vt = ws + WS_VT + ((size_t)bb2 * 128 + h) * 2048 + tin;
#pragma unroll
        for (int q4 = 0; q4 < 4; q4++) {
            ushort8 pk;
#pragma unroll
            for (int e = 0; e < 8; e++) pk[e] = smem[(seg * 32 + q4 * 8 + e) * 136 + h];
            *(ushort8*)(vt + q4 * 8) = pk;   // one full 64B line per lane
        }
    }
}

// ================= K2: causal flash attention =============================
// grid (8 batch, 64 q-tiles); batch == linear_bid % 8 -> pinned per XCD.
// 4 waves split the KV tiles (ti = w, w+4, ...), zero in-loop barriers;
// K/V fragments gathered straight from L2 (K/V per batch = 1 MB bf16).
__global__ __launch_bounds__(256, 2) void attn_kernel(const unsigned short* __restrict__ ws,
        float* __restrict__ out) {
    __shared__ __align__(16) float o_lds[4][32][128];   // 64 KB (first 4KB/wave doubles as P buffer)
    __shared__ float ml[4][2][32];
    int b = blockIdx.x;
    int qi = 63 - (int)blockIdx.y;          // longest blocks first
    int qbase = qi * 32;
    int tid = threadIdx.x, lane = tid & 63, w = tid >> 6;
    int lr = lane & 15, lg = lane >> 4;
    const unsigned short* Qb = ws + WS_Q + (size_t)b * 2048 * 128;
    const unsigned short* Kb = ws + WS_K + (size_t)b * 2048 * 128;
    const unsigned short* Vt = ws + WS_VT + (size_t)b * 128 * 2048;
    char* p_lds = (char*)&o_lds[w][0][0];   // per-wave private 4 KB, swizzled [32][64] bf16

    short8 qf[2][4];
#pragma unroll
    for (int i = 0; i < 2; i++)
#pragma unroll
        for (int kf = 0; kf < 4; kf++)
            qf[i][kf] = *(const short8*)&Qb[(size_t)(qbase + i * 16 + lr) * 128 + kf * 32 + lg * 8];

    f32x4 o[2][8];
#pragma unroll
    for (int i = 0; i < 2; i++)
#pragma unroll
        for (int jn = 0; jn < 8; jn++) o[i][jn] = (f32x4){0.f, 0.f, 0.f, 0.f};
    float mrow[2][4], lrow[2][4];
#pragma unroll
    for (int i = 0; i < 2; i++)
#pragma unroll
        for (int r = 0; r < 4; r++) { mrow[i][r] = -__builtin_inff(); lrow[i][r] = 0.f; }

    int ntiles = qi / 2 + 1;
    for (int ti = w; ti < ntiles; ti += 4) {
        int sb = ti * 64;
        f32x4 s[2][4];
#pragma unroll
        for (int i = 0; i < 2; i++)
#pragma unroll
            for (int nf = 0; nf < 4; nf++) s[i][nf] = (f32x4){0.f, 0.f, 0.f, 0.f};
        {
            short8 kb[4][4];
#pragma unroll
            for (int nf = 0; nf < 4; nf++)
#pragma unroll
                for (int kf = 0; kf < 4; kf++)
                    kb[nf][kf] = *(const short8*)&Kb[(size_t)(sb + nf * 16 + lr) * 128 + kf * 32 + lg * 8];
#pragma unroll
            for (int kf = 0; kf < 4; kf++)
#pragma unroll
                for (int i = 0; i < 2; i++)
#pragma unroll
                    for (int nf = 0; nf < 4; nf++)
                        s[i][nf] = __builtin_amdgcn_mfma_f32_16x16x32_bf16(qf[i][kf], kb[nf][kf], s[i][nf], 0, 0, 0);
        }
        if (sb + 63 > qbase) {   // diagonal tile(s): causal mask
#pragma unroll
            for (int i = 0; i < 2; i++)
#pragma unroll
                for (int nf = 0; nf < 4; nf++)
#pragma unroll
                    for (int r = 0; r < 4; r++) {
                        int sg = sb + nf * 16 + lr;
                        int qg = qbase + i * 16 + (lg << 2) + r;
                        if (sg > qg) s[i][nf][r] = -__builtin_inff();
                    }
        }
        float alpha[2][4];
#pragma unroll
        for (int i = 0; i < 2; i++)
#pragma unroll
            for (int r = 0; r < 4; r++) {
                float pm = fmaxf(fmaxf(s[i][0][r], s[i][1][r]), fmaxf(s[i][2][r], s[i][3][r]));
                pm = fmaxf(pm, __shfl_xor(pm, 1));
                pm = fmaxf(pm, __shfl_xor(pm, 2));
                pm = fmaxf(pm, __shfl_xor(pm, 4));
                pm = fmaxf(pm, __shfl_xor(pm, 8));
                float mn = fmaxf(mrow[i][r], pm);
                alpha[i][r] = __expf(mrow[i][r] - mn);
                mrow[i][r] = mn;
            }
#pragma unroll
        for (int i = 0; i < 2; i++)
#pragma unroll
            for (int r = 0; r < 4; r++) {
                float rs = 0.f;
#pragma unroll
                for (int nf = 0; nf < 4; nf++) {
                    float p = __expf(s[i][nf][r] - mrow[i][r]);
                    s[i][nf][r] = p;
                    rs += p;
                }
                rs += __shfl_xor(rs, 1);
                rs += __shfl_xor(rs, 2);
                rs += __shfl_xor(rs, 4);
                rs += __shfl_xor(rs, 8);
                lrow[i][r] = lrow[i][r] * alpha[i][r] + rs;
            }
#pragma unroll
        for (int i = 0; i < 2; i++)
#pragma unroll
            for (int jn = 0; jn < 8; jn++)
#pragma unroll
                for (int r = 0; r < 4; r++) o[i][jn][r] *= alpha[i][r];
        // P -> per-wave LDS (transpose to A-fragment layout), bf16 swizzled
#pragma unroll
        for (int i = 0; i < 2; i++)
#pragma unroll
            for (int nf = 0; nf < 4; nf++)
#pragma unroll
                for (int r = 0; r < 4; r++) {
                    int row = i * 16 + (lg << 2) + r;
                    int cb2 = (nf * 16 + lr) * 2;
                    *(unsigned short*)(p_lds + swz128(row, cb2)) = f2bf(s[i][nf][r]);
                }
        asm volatile("s_waitcnt lgkmcnt(0)" ::: "memory");  // wave-internal LDS visibility
        short8 pa[2][2];
#pragma unroll
        for (int i = 0; i < 2; i++)
#pragma unroll
            for (int kf = 0; kf < 2; kf++)
                pa[i][kf] = *(const short8*)(p_lds + swz128(i * 16 + lr, kf * 64 + lg * 16));
        short8 vb[8][2];
#pragma unroll
        for (int nf = 0; nf < 8; nf++)
#pragma unroll
            for (int kf = 0; kf < 2; kf++)
                vb[nf][kf] = *(const short8*)&Vt[(size_t)(nf * 16 + lr) * 2048 + sb + kf * 32 + lg * 8];
#pragma unroll
        for (int i = 0; i < 2; i++)
#pragma unroll
            for (int nf = 0; nf < 8; nf++)
#pragma unroll
                for (int kf = 0; kf < 2; kf++)
                    o[i][nf] = __builtin_amdgcn_mfma_f32_16x16x32_bf16(pa[i][kf], vb[nf][kf], o[i][nf], 0, 0, 0);
    }
    // publish per-wave partials
#pragma unroll
    for (int i = 0; i < 2; i++)
#pragma unroll
        for (int r = 0; r < 4; r++) {
            int q = i * 16 + (lg << 2) + r;
            ml[w][0][q] = mrow[i][r];
            ml[w][1][q] = lrow[i][r];
        }
    asm volatile("s_waitcnt lgkmcnt(0)" ::: "memory");  // P region dead before aliased O writes
#pragma unroll
    for (int i = 0; i < 2; i++)
#pragma unroll
        for (int jn = 0; jn < 8; jn++)
#pragma unroll
            for (int r = 0; r < 4; r++)
                o_lds[w][i * 16 + (lg << 2) + r][jn * 16 + lr] = o[i][jn][r];
    __syncthreads();
    // merge the 4 split-KV partials
    int q = tid >> 3, h0 = (tid & 7) << 4;
    float mg = fmaxf(fmaxf(ml[0][0][q], ml[1][0][q]), fmaxf(ml[2][0][q], ml[3][0][q]));
    float scw[4], den = 0.f;
#pragma unroll
    for (int w4 = 0; w4 < 4; w4++) {
        scw[w4] = __expf(ml[w4][0][q] - mg);
        den += scw[w4] * ml[w4][1][q];
    }
    float inv = 1.0f / den;
    float* op = out + ((size_t)b * 2048 + qbase + q) * 128 + h0;
#pragma unroll
    for (int jj = 0; jj < 4; jj++) {
        f32x4 a4 = (f32x4){0.f, 0.f, 0.f, 0.f};
#pragma unroll
        for (int w4 = 0; w4 < 4; w4++) {
            f32x4 v = *(const f32x4*)&o_lds[w4][q][h0 + jj * 4];
            a4 += scw[w4] * v;
        }
        a4 *= inv;
        *(f32x4*)(op + jj * 4) = a4;
    }
}

extern "C" void kernel_launch(void* const* d_in, const int* in_sizes, int n_in,
                              void* d_out, int out_size, void* d_ws, size_t ws_size,
                              hipStream_t stream) {
    (void)in_sizes; (void)n_in; (void)out_size; (void)ws_size;
    const float* x  = (const float*)d_in[0];
    const float* Wq = (const float*)d_in[1];
    const float* bq = (const float*)d_in[2];
    const float* Wk = (const float*)d_in[3];
    const float* bk = (const float*)d_in[4];
    const float* Wv = (const float*)d_in[5];
    const float* bv = (const float*)d_in[6];
    unsigned short* ws = (unsigned short*)d_ws;
    float* out = (float*)d_out;

    wt_kernel<<<96, 256, 0, stream>>>(Wq, Wk, Wv, ws);
    qkv_kernel<<<768, 256, 0, stream>>>(x, bq, bk, bv, ws);
    attn_kernel<<<dim3(8, 64), 256, 0, stream>>>(ws, out);
}

// Round 2
// 107.544 us; speedup vs baseline: 1.3190x; 1.3190x over previous
//
#include <hip/hip_runtime.h>

typedef float f32x4 __attribute__((ext_vector_type(4)));
typedef short short8 __attribute__((ext_vector_type(8)));
typedef unsigned short ushort8 __attribute__((ext_vector_type(8)));

// ---------------- workspace layout (ushort elements) ----------------
// WTt (3 x [64 ks][128 h][32 c] bf16): 0 .. 786432
// Q  ([8*2048][128] bf16):        786432
// K  ([8*2048][128] bf16):        2883584
// Vt ([8][128][2048] bf16):       4980736
#define WS_Q  786432
#define WS_K  2883584
#define WS_VT 4980736
#define NITER 64

__device__ __forceinline__ unsigned short f2bf(float x) {
    unsigned u = __float_as_uint(x);
    u += 0x7FFFu + ((u >> 16) & 1u);      // RNE
    return (unsigned short)(u >> 16);
}

// swizzle for 128-byte rows (attn P buffer)
__device__ __forceinline__ int swz128(int row, int cbyte) {
    return row * 128 + (cbyte ^ ((row & 7) << 4));
}

// ================= K0: W [2048][128] fp32 -> WTt [64 ks][128 h][32 c] bf16
__global__ __launch_bounds__(256) void wt_kernel(const float* __restrict__ Wq,
        const float* __restrict__ Wk, const float* __restrict__ Wv,
        unsigned short* __restrict__ ws) {
    __shared__ __align__(16) unsigned short tile[64][136];
    int mat = blockIdx.x >> 5, ct = blockIdx.x & 31;
    const float* W = (mat == 0) ? Wq : ((mat == 1) ? Wk : Wv);
    int cbase = ct * 64;
    int tid = threadIdx.x;
#pragma unroll
    for (int p = 0; p < 8; p++) {
        int fidx = p * 256 + tid;          // float4 index, 2048 total
        int row = fidx >> 5;               // c within tile (0..63)
        int c4 = (fidx & 31) << 2;         // h (0..124)
        float4 v = *(const float4*)&W[(size_t)(cbase + row) * 128 + c4];
        tile[row][c4 + 0] = f2bf(v.x);
        tile[row][c4 + 1] = f2bf(v.y);
        tile[row][c4 + 2] = f2bf(v.z);
        tile[row][c4 + 3] = f2bf(v.w);
    }
    __syncthreads();
    int h = tid >> 1, seg = tid & 1;
    unsigned short* dst = ws + mat * 262144 + (ct * 2 + seg) * 4096 + h * 32;
#pragma unroll
    for (int q4 = 0; q4 < 4; q4++) {
        ushort8 pk;
#pragma unroll
        for (int e = 0; e < 8; e++) pk[e] = tile[seg * 32 + q4 * 8 + e][h];
        *(ushort8*)(dst + q4 * 8) = pk;
    }
}

// ================= K1: QKV projection, depth-2 pipelined ==================
// M=64 N=128 BK=32; 4 LDS buffers; B via global_load_lds (pre-swizzled src),
// A via split reg-staging (issue at t, ds_write at t+1); counted vmcnt(4).
__global__ __launch_bounds__(256, 3) void qkv_kernel(const float* __restrict__ x,
        const float* __restrict__ bq, const float* __restrict__ bk,
        const float* __restrict__ bv, unsigned short* __restrict__ ws) {
    __shared__ __align__(16) unsigned short lds[4][6144];   // 4 x (A 4KB | B 8KB)
    int bid = blockIdx.x;
    int g = bid / 24, j = bid - g * 24;
    int which = j >> 3;                 // 0=Q 1=K 2=V (3 blocks of one mt share XCD)
    int mt = g * 8 + (j & 7);           // 0..255
    const unsigned short* WTt = ws + which * 262144;
    const float* x0 = x + (size_t)mt * 64 * 2048;
    int tid = threadIdx.x, lane = tid & 63, wid = tid >> 6;
    int lr = lane & 15, lg = lane >> 4;
    int m0 = (wid >> 1) * 32, n0 = (wid & 1) * 64;

    // pin bias loads to the top so the vmcnt queue stays exactly counted
    const float* bias = (which == 0) ? bq : ((which == 1) ? bk : bv);
    float bb[4];
#pragma unroll
    for (int j2 = 0; j2 < 4; j2++) bb[j2] = bias[n0 + j2 * 16 + lr];
    asm volatile("" : "+v"(bb[0]), "+v"(bb[1]), "+v"(bb[2]), "+v"(bb[3]));

    // A staging geometry (reg-staged): thread owns 8 floats of the 64x32 tile
    int rowA = tid >> 2, ca = tid & 3;
    const float* aSrc = x0 + (size_t)rowA * 2048 + ca * 8;
    int aDst = rowA * 64 + ((ca ^ ((rowA >> 1) & 3)) << 4);   // swizzled byte off

    // B staging geometry (DMA): 2 issues/wave, 1KB each, pre-swizzled source
    int bsrc0, bsrc1, bdst0, bdst1;
    {
        int idx0 = (0 * 4 + wid) * 64 + lane;
        int h0 = idx0 >> 2, c0 = idx0 & 3;
        bsrc0 = h0 * 32 + ((c0 ^ ((h0 >> 1) & 3)) << 3);
        bdst0 = (0 * 4 + wid) * 1024;
        int idx1 = (1 * 4 + wid) * 64 + lane;
        int h1 = idx1 >> 2, c1 = idx1 & 3;
        bsrc1 = h1 * 32 + ((c1 ^ ((h1 >> 1) & 3)) << 3);
        bdst1 = (1 * 4 + wid) * 1024;
    }

    // fragment read offsets (bytes, swizzled)
    int aOff0, aOff1, bOff0, bOff1, bOff2, bOff3;
    {
        int r0 = m0 + 0 * 16 + lr; aOff0 = r0 * 64 + ((lg ^ ((r0 >> 1) & 3)) << 4);
        int r1 = m0 + 1 * 16 + lr; aOff1 = r1 * 64 + ((lg ^ ((r1 >> 1) & 3)) << 4);
        int s0 = n0 + 0 * 16 + lr; bOff0 = s0 * 64 + ((lg ^ ((s0 >> 1) & 3)) << 4);
        int s1 = n0 + 1 * 16 + lr; bOff1 = s1 * 64 + ((lg ^ ((s1 >> 1) & 3)) << 4);
        int s2 = n0 + 2 * 16 + lr; bOff2 = s2 * 64 + ((lg ^ ((s2 >> 1) & 3)) << 4);
        int s3 = n0 + 3 * 16 + lr; bOff3 = s3 * 64 + ((lg ^ ((s3 >> 1) & 3)) << 4);
    }

    f32x4 acc[2][4];
#pragma unroll
    for (int i = 0; i < 2; i++)
#pragma unroll
        for (int j3 = 0; j3 < 4; j3++) acc[i][j3] = (f32x4){0.f, 0.f, 0.f, 0.f};
    float4 rA[2][2];

#define ISSUE_A(PAR, T) do { \
        const float* ap_ = aSrc + (T) * 32; \
        rA[PAR][0] = *(const float4*)ap_; \
        rA[PAR][1] = *(const float4*)(ap_ + 4); \
    } while (0)
#define ISSUE_B(BUF, T) do { \
        const unsigned short* bs_ = WTt + (size_t)(T) * 4096; \
        char* bd_ = (char*)&lds[BUF][2048]; \
        __builtin_amdgcn_global_load_lds((const __attribute__((address_space(1))) unsigned*)(bs_ + bsrc0), \
            (__attribute__((address_space(3))) unsigned*)(bd_ + bdst0), 16, 0, 0); \
        __builtin_amdgcn_global_load_lds((const __attribute__((address_space(1))) unsigned*)(bs_ + bsrc1), \
            (__attribute__((address_space(3))) unsigned*)(bd_ + bdst1), 16, 0, 0); \
    } while (0)
#define WRITE_A(PAR, BUF) do { \
        const float* f_ = (const float*)&rA[PAR][0]; \
        ushort8 pk_; \
        pk_[0] = f2bf(f_[0]); pk_[1] = f2bf(f_[1]); pk_[2] = f2bf(f_[2]); pk_[3] = f2bf(f_[3]); \
        pk_[4] = f2bf(f_[4]); pk_[5] = f2bf(f_[5]); pk_[6] = f2bf(f_[6]); pk_[7] = f2bf(f_[7]); \
        *(ushort8*)((char*)&lds[BUF][0] + aDst) = pk_; \
    } while (0)

    // body: reads(t) | issue(t+2) | MFMA(t) | vmcnt | ds_write A(t+1) | barrier
#define QKV_BODY(U, T, STAGE, WRITE, BAR) do { \
        const char* Ab_ = (const char*)&lds[U][0]; \
        const char* Bb_ = (const char*)&lds[U][2048]; \
        short8 av0 = *(const short8*)(Ab_ + aOff0); \
        short8 av1 = *(const short8*)(Ab_ + aOff1); \
        short8 bv0 = *(const short8*)(Bb_ + bOff0); \
        short8 bv1 = *(const short8*)(Bb_ + bOff1); \
        short8 bv2 = *(const short8*)(Bb_ + bOff2); \
        short8 bv3 = *(const short8*)(Bb_ + bOff3); \
        if (STAGE) { ISSUE_A((U) & 1, (T) + 2); ISSUE_B(((U) + 2) & 3, (T) + 2); } \
        acc[0][0] = __builtin_amdgcn_mfma_f32_16x16x32_bf16(av0, bv0, acc[0][0], 0, 0, 0); \
        acc[0][1] = __builtin_amdgcn_mfma_f32_16x16x32_bf16(av0, bv1, acc[0][1], 0, 0, 0); \
        acc[0][2] = __builtin_amdgcn_mfma_f32_16x16x32_bf16(av0, bv2, acc[0][2], 0, 0, 0); \
        acc[0][3] = __builtin_amdgcn_mfma_f32_16x16x32_bf16(av0, bv3, acc[0][3], 0, 0, 0); \
        acc[1][0] = __builtin_amdgcn_mfma_f32_16x16x32_bf16(av1, bv0, acc[1][0], 0, 0, 0); \
        acc[1][1] = __builtin_amdgcn_mfma_f32_16x16x32_bf16(av1, bv1, acc[1][1], 0, 0, 0); \
        acc[1][2] = __builtin_amdgcn_mfma_f32_16x16x32_bf16(av1, bv2, acc[1][2], 0, 0, 0); \
        acc[1][3] = __builtin_amdgcn_mfma_f32_16x16x32_bf16(av1, bv3, acc[1][3], 0, 0, 0); \
        if (STAGE) { asm volatile("s_waitcnt vmcnt(4)" ::: "memory"); } \
        else if (WRITE) { asm volatile("s_waitcnt vmcnt(0)" ::: "memory"); } \
        if (WRITE) { \
            WRITE_A(((U) + 1) & 1, ((U) + 1) & 3); \
            asm volatile("s_waitcnt lgkmcnt(0)" ::: "memory"); \
        } \
        if (BAR) __builtin_amdgcn_s_barrier(); \
    } while (0)

    // prologue: stage tiles 0 and 1
    ISSUE_A(0, 0);
    ISSUE_B(0, 0);
    ISSUE_A(1, 1);
    ISSUE_B(1, 1);
    asm volatile("s_waitcnt vmcnt(4)" ::: "memory");   // A(0),B(0) landed
    WRITE_A(0, 0);
    asm volatile("s_waitcnt lgkmcnt(0)" ::: "memory");
    __builtin_amdgcn_s_barrier();

    for (int to = 0; to < 15; to++) {
        int T0 = to * 4;
        QKV_BODY(0, T0 + 0, true, true, true);
        QKV_BODY(1, T0 + 1, true, true, true);
        QKV_BODY(2, T0 + 2, true, true, true);
        QKV_BODY(3, T0 + 3, true, true, true);
    }
    QKV_BODY(0, 60, true,  true,  true);
    QKV_BODY(1, 61, true,  true,  true);
    QKV_BODY(2, 62, false, true,  true);
    QKV_BODY(3, 63, false, false, false);

    // ----- epilogue -----
    if (which < 2) {
        unsigned short* outp = ws + ((which == 0) ? WS_Q : WS_K);
        float sc = (which == 0) ? 0.08838834764831845f : 1.0f;
#pragma unroll
        for (int i = 0; i < 2; i++)
#pragma unroll
            for (int j3 = 0; j3 < 4; j3++) {
                int h = n0 + j3 * 16 + lr;
#pragma unroll
                for (int r = 0; r < 4; r++) {
                    int t = mt * 64 + m0 + i * 16 + (lg << 2) + r;
                    outp[(size_t)t * 128 + h] = f2bf((acc[i][j3][r] + bb[j3]) * sc);
                }
            }
    } else {
        __syncthreads();
        unsigned short* sm = &lds[0][0];   // [64][136]
#pragma unroll
        for (int i = 0; i < 2; i++)
#pragma unroll
            for (int j3 = 0; j3 < 4; j3++) {
                int h = n0 + j3 * 16 + lr;
#pragma unroll
                for (int r = 0; r < 4; r++) {
                    int tl = m0 + i * 16 + (lg << 2) + r;
                    sm[tl * 136 + h] = f2bf(acc[i][j3][r] + bb[j3]);
                }
            }
        __syncthreads();
        int h = tid & 127, seg = tid >> 7;
        int b2 = mt >> 5;
        int tin = (mt & 31) * 64 + seg * 32;
        unsigned short* vt = ws + WS_VT + ((size_t)b2 * 128 + h) * 2048 + tin;
#pragma unroll
        for (int q4 = 0; q4 < 4; q4++) {
            ushort8 pk;
#pragma unroll
            for (int e = 0; e < 8; e++) pk[e] = sm[(seg * 32 + q4 * 8 + e) * 136 + h];
            *(ushort8*)(vt + q4 * 8) = pk;
        }
    }
#undef QKV_BODY
#undef WRITE_A
#undef ISSUE_B
#undef ISSUE_A
}

// ================= K2: causal flash attention (unchanged from R0) =========
__global__ __launch_bounds__(256, 2) void attn_kernel(const unsigned short* __restrict__ ws,
        float* __restrict__ out) {
    __shared__ __align__(16) float o_lds[4][32][128];   // 64 KB
    __shared__ float ml[4][2][32];
    int b = blockIdx.x;
    int qi = 63 - (int)blockIdx.y;          // longest blocks first
    int qbase = qi * 32;
    int tid = threadIdx.x, lane = tid & 63, w = tid >> 6;
    int lr = lane & 15, lg = lane >> 4;
    const unsigned short* Qb = ws + WS_Q + (size_t)b * 2048 * 128;
    const unsigned short* Kb = ws + WS_K + (size_t)b * 2048 * 128;
    const unsigned short* Vt = ws + WS_VT + (size_t)b * 128 * 2048;
    char* p_lds = (char*)&o_lds[w][0][0];   // per-wave private 4 KB

    short8 qf[2][4];
#pragma unroll
    for (int i = 0; i < 2; i++)
#pragma unroll
        for (int kf = 0; kf < 4; kf++)
            qf[i][kf] = *(const short8*)&Qb[(size_t)(qbase + i * 16 + lr) * 128 + kf * 32 + lg * 8];

    f32x4 o[2][8];
#pragma unroll
    for (int i = 0; i < 2; i++)
#pragma unroll
        for (int jn = 0; jn < 8; jn++) o[i][jn] = (f32x4){0.f, 0.f, 0.f, 0.f};
    float mrow[2][4], lrow[2][4];
#pragma unroll
    for (int i = 0; i < 2; i++)
#pragma unroll
        for (int r = 0; r < 4; r++) { mrow[i][r] = -__builtin_inff(); lrow[i][r] = 0.f; }

    int ntiles = qi / 2 + 1;
    for (int ti = w; ti < ntiles; ti += 4) {
        int sb = ti * 64;
        f32x4 s[2][4];
#pragma unroll
        for (int i = 0; i < 2; i++)
#pragma unroll
            for (int nf = 0; nf < 4; nf++) s[i][nf] = (f32x4){0.f, 0.f, 0.f, 0.f};
        {
            short8 kb[4][4];
#pragma unroll
            for (int nf = 0; nf < 4; nf++)
#pragma unroll
                for (int kf = 0; kf < 4; kf++)
                    kb[nf][kf] = *(const short8*)&Kb[(size_t)(sb + nf * 16 + lr) * 128 + kf * 32 + lg * 8];
#pragma unroll
            for (int kf = 0; kf < 4; kf++)
#pragma unroll
                for (int i = 0; i < 2; i++)
#pragma unroll
                    for (int nf = 0; nf < 4; nf++)
                        s[i][nf] = __builtin_amdgcn_mfma_f32_16x16x32_bf16(qf[i][kf], kb[nf][kf], s[i][nf], 0, 0, 0);
        }
        if (sb + 63 > qbase) {   // diagonal tile(s): causal mask
#pragma unroll
            for (int i = 0; i < 2; i++)
#pragma unroll
                for (int nf = 0; nf < 4; nf++)
#pragma unroll
                    for (int r = 0; r < 4; r++) {
                        int sg = sb + nf * 16 + lr;
                        int qg = qbase + i * 16 + (lg << 2) + r;
                        if (sg > qg) s[i][nf][r] = -__builtin_inff();
                    }
        }
        float alpha[2][4];
#pragma unroll
        for (int i = 0; i < 2; i++)
#pragma unroll
            for (int r = 0; r < 4; r++) {
                float pm = fmaxf(fmaxf(s[i][0][r], s[i][1][r]), fmaxf(s[i][2][r], s[i][3][r]));
                pm = fmaxf(pm, __shfl_xor(pm, 1));
                pm = fmaxf(pm, __shfl_xor(pm, 2));
                pm = fmaxf(pm, __shfl_xor(pm, 4));
                pm = fmaxf(pm, __shfl_xor(pm, 8));
                float mn = fmaxf(mrow[i][r], pm);
                alpha[i][r] = __expf(mrow[i][r] - mn);
                mrow[i][r] = mn;
            }
#pragma unroll
        for (int i = 0; i < 2; i++)
#pragma unroll
            for (int r = 0; r < 4; r++) {
                float rs = 0.f;
#pragma unroll
                for (int nf = 0; nf < 4; nf++) {
                    float p = __expf(s[i][nf][r] - mrow[i][r]);
                    s[i][nf][r] = p;
                    rs += p;
                }
                rs += __shfl_xor(rs, 1);
                rs += __shfl_xor(rs, 2);
                rs += __shfl_xor(rs, 4);
                rs += __shfl_xor(rs, 8);
                lrow[i][r] = lrow[i][r] * alpha[i][r] + rs;
            }
#pragma unroll
        for (int i = 0; i < 2; i++)
#pragma unroll
            for (int jn = 0; jn < 8; jn++)
#pragma unroll
                for (int r = 0; r < 4; r++) o[i][jn][r] *= alpha[i][r];
#pragma unroll
        for (int i = 0; i < 2; i++)
#pragma unroll
            for (int nf = 0; nf < 4; nf++)
#pragma unroll
                for (int r = 0; r < 4; r++) {
                    int row = i * 16 + (lg << 2) + r;
                    int cb2 = (nf * 16 + lr) * 2;
                    *(unsigned short*)(p_lds + swz128(row, cb2)) = f2bf(s[i][nf][r]);
                }
        asm volatile("s_waitcnt lgkmcnt(0)" ::: "memory");
        short8 pa[2][2];
#pragma unroll
        for (int i = 0; i < 2; i++)
#pragma unroll
            for (int kf = 0; kf < 2; kf++)
                pa[i][kf] = *(const short8*)(p_lds + swz128(i * 16 + lr, kf * 64 + lg * 16));
        short8 vb[8][2];
#pragma unroll
        for (int nf = 0; nf < 8; nf++)
#pragma unroll
            for (int kf = 0; kf < 2; kf++)
                vb[nf][kf] = *(const short8*)&Vt[(size_t)(nf * 16 + lr) * 2048 + sb + kf * 32 + lg * 8];
#pragma unroll
        for (int i = 0; i < 2; i++)
#pragma unroll
            for (int nf = 0; nf < 8; nf++)
#pragma unroll
                for (int kf = 0; kf < 2; kf++)
                    o[i][nf] = __builtin_amdgcn_mfma_f32_16x16x32_bf16(pa[i][kf], vb[nf][kf], o[i][nf], 0, 0, 0);
    }
#pragma unroll
    for (int i = 0; i < 2; i++)
#pragma unroll
        for (int r = 0; r < 4; r++) {
            int q = i * 16 + (lg << 2) + r;
            ml[w][0][q] = mrow[i][r];
            ml[w][1][q] = lrow[i][r];
        }
    asm volatile("s_waitcnt lgkmcnt(0)" ::: "memory");
#pragma unroll
    for (int i = 0; i < 2; i++)
#pragma unroll
        for (int jn = 0; jn < 8; jn++)
#pragma unroll
            for (int r = 0; r < 4; r++)
                o_lds[w][i * 16 + (lg << 2) + r][jn * 16 + lr] = o[i][jn][r];
    __syncthreads();
    int q = tid >> 3, h0 = (tid & 7) << 4;
    float mg = fmaxf(fmaxf(ml[0][0][q], ml[1][0][q]), fmaxf(ml[2][0][q], ml[3][0][q]));
    float scw[4], den = 0.f;
#pragma unroll
    for (int w4 = 0; w4 < 4; w4++) {
        scw[w4] = __expf(ml[w4][0][q] - mg);
        den += scw[w4] * ml[w4][1][q];
    }
    float inv = 1.0f / den;
    float* op = out + ((size_t)b * 2048 + qbase + q) * 128 + h0;
#pragma unroll
    for (int jj = 0; jj < 4; jj++) {
        f32x4 a4 = (f32x4){0.f, 0.f, 0.f, 0.f};
#pragma unroll
        for (int w4 = 0; w4 < 4; w4++) {
            f32x4 v = *(const f32x4*)&o_lds[w4][q][h0 + jj * 4];
            a4 += scw[w4] * v;
        }
        a4 *= inv;
        *(f32x4*)(op + jj * 4) = a4;
    }
}

extern "C" void kernel_launch(void* const* d_in, const int* in_sizes, int n_in,
                              void* d_out, int out_size, void* d_ws, size_t ws_size,
                              hipStream_t stream) {
    (void)in_sizes; (void)n_in; (void)out_size; (void)ws_size;
    const float* x  = (const float*)d_in[0];
    const float* Wq = (const float*)d_in[1];
    const float* bq = (const float*)d_in[2];
    const float* Wk = (const float*)d_in[3];
    const float* bk = (const float*)d_in[4];
    const float* Wv = (const float*)d_in[5];
    const float* bv = (const float*)d_in[6];
    unsigned short* ws = (unsigned short*)d_ws;
    float* out = (float*)d_out;

    wt_kernel<<<96, 256, 0, stream>>>(Wq, Wk, Wv, ws);
    qkv_kernel<<<768, 256, 0, stream>>>(x, bq, bk, bv, ws);
    attn_kernel<<<dim3(8, 64), 256, 0, stream>>>(ws, out);
}